// Round 1
// baseline (110.483 us; speedup 1.0000x reference)
//
#include <hip/hip_runtime.h>
#include <math.h>

// CoherentLoss: N=16384 trajectories, grid M ~= 2402 (x uniform, h=0.01).
// Round-7 structure. 3 dispatches (R6 fusion regressed: per-block device-scope
// fences cost more than kernel-boundary flushes):
//  K0 memset: pres bitmap + loss + done counters (8.2 KB)
//  K1 gt_kernel: per-thread prep, windowed |dxq|<=3.5 trapz.
//     NEW vs R5: chunk boundaries aligned to m%4==0 so the LDS gather is
//     ds_read_b128 (4x fewer DS ops, conflicts amortized); exp+rotation fused
//     into one complex recurrence z*=W, W*=d (8 VALU/iter vs 9);
//     CHUNKS 8->16 (1024 blocks = 4 blocks/CU = 16 waves/CU).
//     Aligned over-read past the true window adds points at |dx|>3.5 where
//     exp(-dx^2)<5e-6 (same order as existing truncation); LDS zero-padded to
//     MCAP so reads past M contribute exactly 0.
//  K2 scatter_loss: chunk-sum partials in regs, recompute vals, popcount-rank
//     scatter, in-kernel grid barrier (64 blocks, co-resident), loss + sqrt.

#define PRES_WORDS 1024          // 65536 bins / 64 bits
#define PRES_BITS  65536
#define PRES_OFF   32768
#define CHUNKS     16            // pow2: chunk split is shifts only
#define MCAP       2432          // >= aligned-up M (2404), LDS wpsi capacity
#define WINR       3.5f          // exp(-12.25)=4.8e-6 -> truncation negligible
#define NORM       0.8932438417380023f   // (2/pi)^0.25

__global__ void __launch_bounds__(256) gt_kernel(
    const float* __restrict__ q_re, const float* __restrict__ q_im,
    const float* __restrict__ p_re, const float* __restrict__ p_im,
    const float* __restrict__ x, const float* __restrict__ psi,
    unsigned long long* __restrict__ pres,
    float* __restrict__ bre, float* __restrict__ bim,
    float* __restrict__ gpre, float* __restrict__ gpim, int n, int M)
{
    __shared__ __align__(16) float swpsi[MCAP];  // 9.5 KB: trapz weight*psi*norm
    int tid = threadIdx.x;
    float x0 = x[0];
    float h  = x[1] - x0;                    // uniform step (~0.01)
    for (int m = tid; m < MCAP; m += 256) {  // zero-pad [M, MCAP)
        float v = 0.0f;
        if (m < M) {
            float w = (m == 0 || m == M - 1) ? 0.5f * h : h;
            v = w * psi[m] * NORM;
        }
        swpsi[m] = v;
    }
    __syncthreads();
    int t = blockIdx.x * 256 + tid;
    if (t >= n) return;
    // local prep: bin centers from this thread's own inputs only
    float qi = q_im[t], pr = p_re[t];
    float qf = q_re[t] - 0.5f * p_im[t];     // g = 1, exact pow2 ops
    float pf = 2.0f * qi + pr;
    float qb = floorf((qf + 8.0f) / 0.125f);     // dq exact pow2
    float pb = floorf((pf + 10.0f) / 0.15625f);  // dp = 5/32 exact
    float qcn = (qb + 0.5f) * 0.125f - 8.0f;
    float pcn = (pb + 0.5f) * 0.15625f - 10.0f;
    if (blockIdx.y == 0) {                   // build presence bitmap + zero binned
        int b = (int)(qb * 128.0f + pb);
        int pidx = min(max(b + PRES_OFF, 0), PRES_BITS - 1);
        atomicOr(&pres[pidx >> 6], 1ull << (pidx & 63));
        bre[t] = 0.0f; bim[t] = 0.0f;
    }
    // window [mlo, mhi): |x[m] - qc| <= WINR; aligned outward to m%4==0
    float inv_h = 1.0f / h;
    int mlo = max(0, (int)((qcn - WINR - x0) * inv_h) - 1) & ~3;
    int mhi = min(M, (int)((qcn + WINR - x0) * inv_h) + 2);
    mhi = (mhi + 3) & ~3;                    // <= 2404 <= MCAP (zero-padded)
    int G = (mhi - mlo) >> 2; if (G < 0) G = 0;   // 4-point groups
    int c = blockIdx.y;
    int ms = mlo + (((G * c) >> 4) << 2);         // CHUNKS=16 -> >>4
    int me = mlo + (((G * (c + 1)) >> 4) << 2);
    // complex recurrence: z_m = e_m*(cos th_m - i sin th_m), th = pcn*dx
    //   z_{m+1} = z_m * W_m,  W_m = u_m*(cd - i sd),  W_{m+1} = d*W_m
    float dx0 = fmaf((float)ms, h, x0 - qcn);
    float e   = __expf(-dx0 * dx0);
    float u   = __expf(-h * (dx0 + dx0 + h));
    float d   = __expf(-2.0f * h * h);
    float sn, cs, sd, cd;
    __sincosf(pcn * dx0, &sn, &cs);
    __sincosf(pcn * h, &sd, &cd);
    float zre = e * cs,  zim = -e * sn;
    float Wre = u * cd,  Wim = -u * sd;
    float sre = 0.0f, sim = 0.0f;
#define STEP(WV) {                                   \
        sre = fmaf((WV), zre, sre);                  \
        sim = fmaf((WV), zim, sim);                  \
        float zt = fmaf(zre, Wre, -(zim * Wim));     \
        zim = fmaf(zre, Wim, zim * Wre);             \
        zre = zt;                                    \
        Wre *= d; Wim *= d; }
    for (int m = ms; m < me; m += 4) {
        float4 wv = *(const float4*)(swpsi + m);     // ds_read_b128, 16B aligned
        STEP(wv.x) STEP(wv.y) STEP(wv.z) STEP(wv.w)
    }
#undef STEP
    gpre[c * n + t] = sre;                   // exact write, no zero needed
    gpim[c * n + t] = sim;
}

// 64 blocks (co-resident on 256 CUs): chunk-sum gt in regs, recompute vals,
// rank-scatter into binned, grid barrier, per-slice loss, last block sqrts.
__global__ void __launch_bounds__(256) scatter_loss_kernel(
    const float* __restrict__ f_re, const float* __restrict__ f_im,
    const float* __restrict__ q_re, const float* __restrict__ q_im,
    const float* __restrict__ p_re, const float* __restrict__ p_im,
    const unsigned long long* __restrict__ pres,
    float* __restrict__ bre, float* __restrict__ bim,
    const float* __restrict__ gpre, const float* __restrict__ gpim,
    int* __restrict__ k3done, float* __restrict__ loss, int* __restrict__ fin,
    float* __restrict__ out, int n)
{
    __shared__ int lbase[PRES_WORDS];        // exclusive rank base per 64-bin word
    int tid = threadIdx.x;
    if (tid < 64) {
        int cum[16];
        int tot = 0;
        for (int k = 0; k < 16; k++) { cum[k] = tot; tot += __popcll(pres[tid * 16 + k]); }
        int run = tot;
        for (int off = 1; off < 64; off <<= 1) {
            int up = __shfl_up(run, off);
            if (tid >= off) run += up;
        }
        int excl = run - tot;
        for (int k = 0; k < 16; k++) lbase[tid * 16 + k] = excl + cum[k];
    }
    __syncthreads();
    int t = blockIdx.x * 256 + tid;
    // chunk-sum this thread's gt (kernel boundary made partials visible)
    float sre = 0.0f, sim = 0.0f;
    for (int c = 0; c < CHUNKS; c++) {
        sre += gpre[c * n + t];
        sim += gpim[c * n + t];
    }
    // recompute bin + vals, scatter into compact-rank binned accumulators
    float qi = q_im[t], pr = p_re[t];
    float qf = q_re[t] - 0.5f * p_im[t];
    float pf = 2.0f * qi + pr;
    float qb = floorf((qf + 8.0f) / 0.125f);
    float pb = floorf((pf + 10.0f) / 0.15625f);
    int b = (int)(qb * 128.0f + pb);
    int pidx = min(max(b + PRES_OFF, 0), PRES_BITS - 1);
    int w = pidx >> 6, bit = pidx & 63;
    unsigned long long below = pres[w] & ((bit == 0) ? 0ull : (~0ull >> (64 - bit)));
    int cid = lbase[w] + __popcll(below);
    float ea = NORM * expf(qi * qi);
    float s, c2;
    __sincosf(pr * qi, &s, &c2);
    float prr = fminf(fmaxf(ea * c2, -100.0f), 100.0f);
    float pri = fminf(fmaxf(ea * s, -100.0f), 100.0f);
    float fr = f_re[t], fi = f_im[t];
    atomicAdd(&bre[cid], prr * fr - pri * fi);
    atomicAdd(&bim[cid], prr * fi + pri * fr);
    // grid barrier: 64 blocks, all co-resident (grid << CU count)
    __threadfence();
    __syncthreads();
    if (tid == 0) {
        __hip_atomic_fetch_add(k3done, 1, __ATOMIC_ACQ_REL, __HIP_MEMORY_SCOPE_AGENT);
        while (__hip_atomic_load(k3done, __ATOMIC_ACQUIRE, __HIP_MEMORY_SCOPE_AGENT)
               < (int)gridDim.x)
            __builtin_amdgcn_s_sleep(4);
    }
    __syncthreads();
    // loss over this block's slice; atomic loads bypass stale L1
    float brt  = __hip_atomic_load(&bre[t], __ATOMIC_RELAXED, __HIP_MEMORY_SCOPE_AGENT);
    float bit2 = __hip_atomic_load(&bim[t], __ATOMIC_RELAXED, __HIP_MEMORY_SCOPE_AGENT);
    float dre = brt - sre;
    float dim = bit2 - sim;
    float v = dre * dre + dim * dim;
#pragma unroll
    for (int off = 32; off > 0; off >>= 1) v += __shfl_down(v, off);
    __shared__ float l[4];
    int wv = tid >> 6, ln = tid & 63;
    if (ln == 0) l[wv] = v;
    __syncthreads();
    if (tid == 0) {
        __hip_atomic_fetch_add(loss, l[0] + l[1] + l[2] + l[3],
                               __ATOMIC_ACQ_REL, __HIP_MEMORY_SCOPE_AGENT);
        int old = __hip_atomic_fetch_add(fin, 1, __ATOMIC_ACQ_REL,
                                         __HIP_MEMORY_SCOPE_AGENT);
        if (old == (int)gridDim.x - 1) {     // last block: all adds visible
            out[0] = sqrtf(__hip_atomic_load(loss, __ATOMIC_ACQUIRE,
                                             __HIP_MEMORY_SCOPE_AGENT));
        }
    }
}

extern "C" void kernel_launch(void* const* d_in, const int* in_sizes, int n_in,
                              void* d_out, int out_size, void* d_ws, size_t ws_size,
                              hipStream_t stream)
{
    const float* f_re = (const float*)d_in[0];
    const float* f_im = (const float*)d_in[1];
    const float* q_re = (const float*)d_in[2];
    const float* q_im = (const float*)d_in[3];
    const float* p_re = (const float*)d_in[4];
    const float* p_im = (const float*)d_in[5];
    const float* x    = (const float*)d_in[6];
    const float* psi  = (const float*)d_in[7];
    int n = in_sizes[0];   // 16384
    int M = in_sizes[6];   // ~2402 (aligned-up <= MCAP)

    // workspace layout
    float* gpre = (float*)d_ws;                         // CHUNKS*n
    float* gpim = gpre + (size_t)CHUNKS * n;            // CHUNKS*n
    float* bre  = gpim + (size_t)CHUNKS * n;            // n
    float* bim  = bre + n;                              // n
    unsigned long long* pres = (unsigned long long*)(bim + n); // 1024 u64
    float* loss    = (float*)(pres + PRES_WORDS);
    int*   k3done  = (int*)(loss + 1);
    int*   fin     = k3done + 1;

    // zero pres + loss + counters (8.2 KB)
    hipMemsetAsync(pres, 0, PRES_WORDS * sizeof(unsigned long long) + 12, stream);

    int nb = (n + 255) / 256;   // 64 -> gt grid 64 x 16 = 1024 blocks, 4/CU
    gt_kernel<<<dim3(nb, CHUNKS), 256, 0, stream>>>(q_re, q_im, p_re, p_im, x, psi,
                                                    pres, bre, bim, gpre, gpim, n, M);
    scatter_loss_kernel<<<nb, 256, 0, stream>>>(f_re, f_im, q_re, q_im, p_re, p_im,
                                                pres, bre, bim, gpre, gpim,
                                                k3done, loss, fin, (float*)d_out, n);
}

// Round 2
// 109.977 us; speedup vs baseline: 1.0046x; 1.0046x over previous
//
#include <hip/hip_runtime.h>
#include <math.h>

// CoherentLoss: N=16384 trajectories, grid M ~= 2402 (x uniform, h=0.01).
// Round-8 structure. 3 dispatches (R6 fusion regressed: per-block device-scope
// fences cost more than kernel-boundary flushes):
//  K0 memset: pres bitmap + loss + done counters (8.2 KB)
//  K1 gt_kernel: per-thread prep, windowed |dxq|<=3.5 trapz.
//     Loop body (kept from R7): chunk boundaries aligned to m%4==0 so the LDS
//     gather is ds_read_b128 (4x fewer DS ops); exp+rotation fused into one
//     complex recurrence z*=W, W*=d (8 VALU/iter).
//     Reverted from R7: CHUNKS back 16->8 (R7's 16 doubled per-thread prep,
//     partial traffic, and scatter chunk-sum; net -3.8 us regression).
//     Aligned over-read past the true window adds points at |dx|>3.5 where
//     exp(-dx^2)<5e-6 (same order as existing truncation); LDS zero-padded to
//     MCAP so reads past M contribute exactly 0.
//  K2 scatter_loss: chunk-sum partials in regs, recompute vals, popcount-rank
//     scatter, in-kernel grid barrier (64 blocks, co-resident), loss + sqrt.

#define PRES_WORDS 1024          // 65536 bins / 64 bits
#define PRES_BITS  65536
#define PRES_OFF   32768
#define CHUNKS     8             // pow2: chunk split is shifts only
#define MCAP       2432          // >= aligned-up M (2404), LDS wpsi capacity
#define WINR       3.5f          // exp(-12.25)=4.8e-6 -> truncation negligible
#define NORM       0.8932438417380023f   // (2/pi)^0.25

__global__ void __launch_bounds__(256) gt_kernel(
    const float* __restrict__ q_re, const float* __restrict__ q_im,
    const float* __restrict__ p_re, const float* __restrict__ p_im,
    const float* __restrict__ x, const float* __restrict__ psi,
    unsigned long long* __restrict__ pres,
    float* __restrict__ bre, float* __restrict__ bim,
    float* __restrict__ gpre, float* __restrict__ gpim, int n, int M)
{
    __shared__ __align__(16) float swpsi[MCAP];  // 9.5 KB: trapz weight*psi*norm
    int tid = threadIdx.x;
    float x0 = x[0];
    float h  = x[1] - x0;                    // uniform step (~0.01)
    for (int m = tid; m < MCAP; m += 256) {  // zero-pad [M, MCAP)
        float v = 0.0f;
        if (m < M) {
            float w = (m == 0 || m == M - 1) ? 0.5f * h : h;
            v = w * psi[m] * NORM;
        }
        swpsi[m] = v;
    }
    __syncthreads();
    int t = blockIdx.x * 256 + tid;
    if (t >= n) return;
    // local prep: bin centers from this thread's own inputs only
    float qi = q_im[t], pr = p_re[t];
    float qf = q_re[t] - 0.5f * p_im[t];     // g = 1, exact pow2 ops
    float pf = 2.0f * qi + pr;
    float qb = floorf((qf + 8.0f) / 0.125f);     // dq exact pow2
    float pb = floorf((pf + 10.0f) / 0.15625f);  // dp = 5/32 exact
    float qcn = (qb + 0.5f) * 0.125f - 8.0f;
    float pcn = (pb + 0.5f) * 0.15625f - 10.0f;
    if (blockIdx.y == 0) {                   // build presence bitmap + zero binned
        int b = (int)(qb * 128.0f + pb);
        int pidx = min(max(b + PRES_OFF, 0), PRES_BITS - 1);
        atomicOr(&pres[pidx >> 6], 1ull << (pidx & 63));
        bre[t] = 0.0f; bim[t] = 0.0f;
    }
    // window [mlo, mhi): |x[m] - qc| <= WINR; aligned outward to m%4==0
    float inv_h = 1.0f / h;
    int mlo = max(0, (int)((qcn - WINR - x0) * inv_h) - 1) & ~3;
    int mhi = min(M, (int)((qcn + WINR - x0) * inv_h) + 2);
    mhi = (mhi + 3) & ~3;                    // <= 2404 <= MCAP (zero-padded)
    int G = (mhi - mlo) >> 2; if (G < 0) G = 0;   // 4-point groups
    int c = blockIdx.y;
    int ms = mlo + (((G * c) >> 3) << 2);         // CHUNKS=8 -> >>3
    int me = mlo + (((G * (c + 1)) >> 3) << 2);
    // complex recurrence: z_m = e_m*(cos th_m - i sin th_m), th = pcn*dx
    //   z_{m+1} = z_m * W_m,  W_m = u_m*(cd - i sd),  W_{m+1} = d*W_m
    float dx0 = fmaf((float)ms, h, x0 - qcn);
    float e   = __expf(-dx0 * dx0);
    float u   = __expf(-h * (dx0 + dx0 + h));
    float d   = __expf(-2.0f * h * h);
    float sn, cs, sd, cd;
    __sincosf(pcn * dx0, &sn, &cs);
    __sincosf(pcn * h, &sd, &cd);
    float zre = e * cs,  zim = -e * sn;
    float Wre = u * cd,  Wim = -u * sd;
    float sre = 0.0f, sim = 0.0f;
#define STEP(WV) {                                   \
        sre = fmaf((WV), zre, sre);                  \
        sim = fmaf((WV), zim, sim);                  \
        float zt = fmaf(zre, Wre, -(zim * Wim));     \
        zim = fmaf(zre, Wim, zim * Wre);             \
        zre = zt;                                    \
        Wre *= d; Wim *= d; }
    for (int m = ms; m < me; m += 4) {
        float4 wv = *(const float4*)(swpsi + m);     // ds_read_b128, 16B aligned
        STEP(wv.x) STEP(wv.y) STEP(wv.z) STEP(wv.w)
    }
#undef STEP
    gpre[c * n + t] = sre;                   // exact write, no zero needed
    gpim[c * n + t] = sim;
}

// 64 blocks (co-resident on 256 CUs): chunk-sum gt in regs, recompute vals,
// rank-scatter into binned, grid barrier, per-slice loss, last block sqrts.
__global__ void __launch_bounds__(256) scatter_loss_kernel(
    const float* __restrict__ f_re, const float* __restrict__ f_im,
    const float* __restrict__ q_re, const float* __restrict__ q_im,
    const float* __restrict__ p_re, const float* __restrict__ p_im,
    const unsigned long long* __restrict__ pres,
    float* __restrict__ bre, float* __restrict__ bim,
    const float* __restrict__ gpre, const float* __restrict__ gpim,
    int* __restrict__ k3done, float* __restrict__ loss, int* __restrict__ fin,
    float* __restrict__ out, int n)
{
    __shared__ int lbase[PRES_WORDS];        // exclusive rank base per 64-bin word
    int tid = threadIdx.x;
    if (tid < 64) {
        int cum[16];
        int tot = 0;
        for (int k = 0; k < 16; k++) { cum[k] = tot; tot += __popcll(pres[tid * 16 + k]); }
        int run = tot;
        for (int off = 1; off < 64; off <<= 1) {
            int up = __shfl_up(run, off);
            if (tid >= off) run += up;
        }
        int excl = run - tot;
        for (int k = 0; k < 16; k++) lbase[tid * 16 + k] = excl + cum[k];
    }
    __syncthreads();
    int t = blockIdx.x * 256 + tid;
    // chunk-sum this thread's gt (kernel boundary made partials visible)
    float sre = 0.0f, sim = 0.0f;
    for (int c = 0; c < CHUNKS; c++) {
        sre += gpre[c * n + t];
        sim += gpim[c * n + t];
    }
    // recompute bin + vals, scatter into compact-rank binned accumulators
    float qi = q_im[t], pr = p_re[t];
    float qf = q_re[t] - 0.5f * p_im[t];
    float pf = 2.0f * qi + pr;
    float qb = floorf((qf + 8.0f) / 0.125f);
    float pb = floorf((pf + 10.0f) / 0.15625f);
    int b = (int)(qb * 128.0f + pb);
    int pidx = min(max(b + PRES_OFF, 0), PRES_BITS - 1);
    int w = pidx >> 6, bit = pidx & 63;
    unsigned long long below = pres[w] & ((bit == 0) ? 0ull : (~0ull >> (64 - bit)));
    int cid = lbase[w] + __popcll(below);
    float ea = NORM * expf(qi * qi);
    float s, c2;
    __sincosf(pr * qi, &s, &c2);
    float prr = fminf(fmaxf(ea * c2, -100.0f), 100.0f);
    float pri = fminf(fmaxf(ea * s, -100.0f), 100.0f);
    float fr = f_re[t], fi = f_im[t];
    atomicAdd(&bre[cid], prr * fr - pri * fi);
    atomicAdd(&bim[cid], prr * fi + pri * fr);
    // grid barrier: 64 blocks, all co-resident (grid << CU count)
    __threadfence();
    __syncthreads();
    if (tid == 0) {
        __hip_atomic_fetch_add(k3done, 1, __ATOMIC_ACQ_REL, __HIP_MEMORY_SCOPE_AGENT);
        while (__hip_atomic_load(k3done, __ATOMIC_ACQUIRE, __HIP_MEMORY_SCOPE_AGENT)
               < (int)gridDim.x)
            __builtin_amdgcn_s_sleep(4);
    }
    __syncthreads();
    // loss over this block's slice; atomic loads bypass stale L1
    float brt  = __hip_atomic_load(&bre[t], __ATOMIC_RELAXED, __HIP_MEMORY_SCOPE_AGENT);
    float bit2 = __hip_atomic_load(&bim[t], __ATOMIC_RELAXED, __HIP_MEMORY_SCOPE_AGENT);
    float dre = brt - sre;
    float dim = bit2 - sim;
    float v = dre * dre + dim * dim;
#pragma unroll
    for (int off = 32; off > 0; off >>= 1) v += __shfl_down(v, off);
    __shared__ float l[4];
    int wv = tid >> 6, ln = tid & 63;
    if (ln == 0) l[wv] = v;
    __syncthreads();
    if (tid == 0) {
        __hip_atomic_fetch_add(loss, l[0] + l[1] + l[2] + l[3],
                               __ATOMIC_ACQ_REL, __HIP_MEMORY_SCOPE_AGENT);
        int old = __hip_atomic_fetch_add(fin, 1, __ATOMIC_ACQ_REL,
                                         __HIP_MEMORY_SCOPE_AGENT);
        if (old == (int)gridDim.x - 1) {     // last block: all adds visible
            out[0] = sqrtf(__hip_atomic_load(loss, __ATOMIC_ACQUIRE,
                                             __HIP_MEMORY_SCOPE_AGENT));
        }
    }
}

extern "C" void kernel_launch(void* const* d_in, const int* in_sizes, int n_in,
                              void* d_out, int out_size, void* d_ws, size_t ws_size,
                              hipStream_t stream)
{
    const float* f_re = (const float*)d_in[0];
    const float* f_im = (const float*)d_in[1];
    const float* q_re = (const float*)d_in[2];
    const float* q_im = (const float*)d_in[3];
    const float* p_re = (const float*)d_in[4];
    const float* p_im = (const float*)d_in[5];
    const float* x    = (const float*)d_in[6];
    const float* psi  = (const float*)d_in[7];
    int n = in_sizes[0];   // 16384
    int M = in_sizes[6];   // ~2402 (aligned-up <= MCAP)

    // workspace layout
    float* gpre = (float*)d_ws;                         // CHUNKS*n
    float* gpim = gpre + (size_t)CHUNKS * n;            // CHUNKS*n
    float* bre  = gpim + (size_t)CHUNKS * n;            // n
    float* bim  = bre + n;                              // n
    unsigned long long* pres = (unsigned long long*)(bim + n); // 1024 u64
    float* loss    = (float*)(pres + PRES_WORDS);
    int*   k3done  = (int*)(loss + 1);
    int*   fin     = k3done + 1;

    // zero pres + loss + counters (8.2 KB)
    hipMemsetAsync(pres, 0, PRES_WORDS * sizeof(unsigned long long) + 12, stream);

    int nb = (n + 255) / 256;   // 64 -> gt grid 64 x 8 = 512 blocks, 2/CU
    gt_kernel<<<dim3(nb, CHUNKS), 256, 0, stream>>>(q_re, q_im, p_re, p_im, x, psi,
                                                    pres, bre, bim, gpre, gpim, n, M);
    scatter_loss_kernel<<<nb, 256, 0, stream>>>(f_re, f_im, q_re, q_im, p_re, p_im,
                                                pres, bre, bim, gpre, gpim,
                                                k3done, loss, fin, (float*)d_out, n);
}

// Round 3
// 107.046 us; speedup vs baseline: 1.0321x; 1.0274x over previous
//
#include <hip/hip_runtime.h>
#include <math.h>

// CoherentLoss: N=16384 trajectories, grid M ~= 2402 (x uniform, h=0.01).
// Round-9: full revert to the best-measured R5 structure (106.7 us this
// session). Post-mortem of R7/R8: the ds_read_b128 + fused-complex-recurrence
// loop body regressed ~3 us (R7 110.5, R8 isolated CHUNKS and stayed 110.0) --
// the fused z<-z*W chain adds 2-dependent-fma latency per point that 2
// waves/SIMD can't hide, outweighing the 4x-fewer-DS-ops win. Reverted.
// 3 dispatches (R6 fusion regressed: per-block device-scope fences for
// cross-XCD coherence cost far more than kernel-boundary flushes):
//  K0 memset: pres bitmap + loss + done counters (8.2 KB)
//  K1 gt_kernel: per-thread prep (local qc/pc, y==0 builds pres + zeroes
//     binned), windowed |dxq|<=3.5 trapz via exp/rot recurrences (no trans in
//     loop), chunked over blockIdx.y, exact-write partials
//  K2 scatter_loss: chunk-sum partials in regs, recompute vals, popcount-rank
//     scatter, in-kernel grid barrier (64 blocks, co-resident), loss + sqrt.

#define PRES_WORDS 1024          // 65536 bins / 64 bits
#define PRES_BITS  65536
#define PRES_OFF   32768
#define CHUNKS     8
#define MCAP       2432          // >= M, LDS wpsi capacity
#define WINR       3.5f          // exp(-12.25)=4.8e-6 -> truncation negligible
#define NORM       0.8932438417380023f   // (2/pi)^0.25

__global__ void __launch_bounds__(256) gt_kernel(
    const float* __restrict__ q_re, const float* __restrict__ q_im,
    const float* __restrict__ p_re, const float* __restrict__ p_im,
    const float* __restrict__ x, const float* __restrict__ psi,
    unsigned long long* __restrict__ pres,
    float* __restrict__ bre, float* __restrict__ bim,
    float* __restrict__ gpre, float* __restrict__ gpim, int n, int M)
{
    __shared__ float swpsi[MCAP];            // 9.7 KB: trapz weight * psi * norm
    int tid = threadIdx.x;
    float x0 = x[0];
    float h  = x[1] - x0;                    // uniform step (~0.01)
    for (int m = tid; m < M; m += 256) {
        float w = (m == 0 || m == M - 1) ? 0.5f * h : h;
        swpsi[m] = w * psi[m] * NORM;
    }
    __syncthreads();
    int t = blockIdx.x * 256 + tid;
    if (t >= n) return;
    // local prep: bin centers from this thread's own inputs only
    float qi = q_im[t], pr = p_re[t];
    float qf = q_re[t] - 0.5f * p_im[t];     // g = 1, exact pow2 ops
    float pf = 2.0f * qi + pr;
    float qb = floorf((qf + 8.0f) / 0.125f);     // dq exact pow2
    float pb = floorf((pf + 10.0f) / 0.15625f);  // dp = 5/32 exact
    float qcn = (qb + 0.5f) * 0.125f - 8.0f;
    float pcn = (pb + 0.5f) * 0.15625f - 10.0f;
    if (blockIdx.y == 0) {                   // build presence bitmap + zero binned
        int b = (int)(qb * 128.0f + pb);
        int pidx = min(max(b + PRES_OFF, 0), PRES_BITS - 1);
        atomicOr(&pres[pidx >> 6], 1ull << (pidx & 63));
        bre[t] = 0.0f; bim[t] = 0.0f;
    }
    // window [mlo, mhi): |x[m] - qc| <= WINR; x[m] = x0 + m*h
    float inv_h = 1.0f / h;
    int mlo = max(0, (int)((qcn - WINR - x0) * inv_h) - 1);
    int mhi = min(M, (int)((qcn + WINR - x0) * inv_h) + 2);
    int len = mhi - mlo; if (len < 0) len = 0;
    int c = blockIdx.y;
    int ms = mlo + (len * c) / CHUNKS;
    int me = mlo + (len * (c + 1)) / CHUNKS;
    // recurrences: e_m = exp(-dx_m^2) via e*=u, u*=d; (sn,cs) rotation by pcn*h
    float dx0 = fmaf((float)ms, h, x0 - qcn);
    float e   = __expf(-dx0 * dx0);
    float u   = __expf(-h * (dx0 + dx0 + h));
    float d   = __expf(-2.0f * h * h);
    float sn, cs, sd, cd;
    __sincosf(pcn * dx0, &sn, &cs);
    __sincosf(pcn * h, &sd, &cd);
    float sre = 0.0f, sim = 0.0f;
    for (int m = ms; m < me; m++) {
        float w = swpsi[m];                  // LDS gather
        float tv = e * w;
        sre = fmaf(tv, cs, sre);             // integrand: w*e*(cos - i sin)
        sim = fmaf(-tv, sn, sim);
        e *= u; u *= d;                      // exp recurrence
        float cn = fmaf(cs, cd, -sn * sd);   // rotation recurrence
        sn = fmaf(sn, cd, cs * sd);
        cs = cn;
    }
    gpre[c * n + t] = sre;                   // exact write, no zero needed
    gpim[c * n + t] = sim;
}

// 64 blocks (co-resident on 256 CUs): chunk-sum gt in regs, recompute vals,
// rank-scatter into binned, grid barrier, per-slice loss, last block sqrts.
__global__ void __launch_bounds__(256) scatter_loss_kernel(
    const float* __restrict__ f_re, const float* __restrict__ f_im,
    const float* __restrict__ q_re, const float* __restrict__ q_im,
    const float* __restrict__ p_re, const float* __restrict__ p_im,
    const unsigned long long* __restrict__ pres,
    float* __restrict__ bre, float* __restrict__ bim,
    const float* __restrict__ gpre, const float* __restrict__ gpim,
    int* __restrict__ k3done, float* __restrict__ loss, int* __restrict__ fin,
    float* __restrict__ out, int n)
{
    __shared__ int lbase[PRES_WORDS];        // exclusive rank base per 64-bin word
    int tid = threadIdx.x;
    if (tid < 64) {
        int cum[16];
        int tot = 0;
        for (int k = 0; k < 16; k++) { cum[k] = tot; tot += __popcll(pres[tid * 16 + k]); }
        int run = tot;
        for (int off = 1; off < 64; off <<= 1) {
            int up = __shfl_up(run, off);
            if (tid >= off) run += up;
        }
        int excl = run - tot;
        for (int k = 0; k < 16; k++) lbase[tid * 16 + k] = excl + cum[k];
    }
    __syncthreads();
    int t = blockIdx.x * 256 + tid;
    // chunk-sum this thread's gt (kernel boundary made partials visible)
    float sre = 0.0f, sim = 0.0f;
    for (int c = 0; c < CHUNKS; c++) {
        sre += gpre[c * n + t];
        sim += gpim[c * n + t];
    }
    // recompute bin + vals, scatter into compact-rank binned accumulators
    float qi = q_im[t], pr = p_re[t];
    float qf = q_re[t] - 0.5f * p_im[t];
    float pf = 2.0f * qi + pr;
    float qb = floorf((qf + 8.0f) / 0.125f);
    float pb = floorf((pf + 10.0f) / 0.15625f);
    int b = (int)(qb * 128.0f + pb);
    int pidx = min(max(b + PRES_OFF, 0), PRES_BITS - 1);
    int w = pidx >> 6, bit = pidx & 63;
    unsigned long long below = pres[w] & ((bit == 0) ? 0ull : (~0ull >> (64 - bit)));
    int cid = lbase[w] + __popcll(below);
    float ea = NORM * expf(qi * qi);
    float s, c2;
    __sincosf(pr * qi, &s, &c2);
    float prr = fminf(fmaxf(ea * c2, -100.0f), 100.0f);
    float pri = fminf(fmaxf(ea * s, -100.0f), 100.0f);
    float fr = f_re[t], fi = f_im[t];
    atomicAdd(&bre[cid], prr * fr - pri * fi);
    atomicAdd(&bim[cid], prr * fi + pri * fr);
    // grid barrier: 64 blocks, all co-resident (grid << CU count)
    __threadfence();
    __syncthreads();
    if (tid == 0) {
        __hip_atomic_fetch_add(k3done, 1, __ATOMIC_ACQ_REL, __HIP_MEMORY_SCOPE_AGENT);
        while (__hip_atomic_load(k3done, __ATOMIC_ACQUIRE, __HIP_MEMORY_SCOPE_AGENT)
               < (int)gridDim.x)
            __builtin_amdgcn_s_sleep(4);
    }
    __syncthreads();
    // loss over this block's slice; atomic loads bypass stale L1
    float brt  = __hip_atomic_load(&bre[t], __ATOMIC_RELAXED, __HIP_MEMORY_SCOPE_AGENT);
    float bit2 = __hip_atomic_load(&bim[t], __ATOMIC_RELAXED, __HIP_MEMORY_SCOPE_AGENT);
    float dre = brt - sre;
    float dim = bit2 - sim;
    float v = dre * dre + dim * dim;
#pragma unroll
    for (int off = 32; off > 0; off >>= 1) v += __shfl_down(v, off);
    __shared__ float l[4];
    int wv = tid >> 6, ln = tid & 63;
    if (ln == 0) l[wv] = v;
    __syncthreads();
    if (tid == 0) {
        __hip_atomic_fetch_add(loss, l[0] + l[1] + l[2] + l[3],
                               __ATOMIC_ACQ_REL, __HIP_MEMORY_SCOPE_AGENT);
        int old = __hip_atomic_fetch_add(fin, 1, __ATOMIC_ACQ_REL,
                                         __HIP_MEMORY_SCOPE_AGENT);
        if (old == (int)gridDim.x - 1) {     // last block: all adds visible
            out[0] = sqrtf(__hip_atomic_load(loss, __ATOMIC_ACQUIRE,
                                             __HIP_MEMORY_SCOPE_AGENT));
        }
    }
}

extern "C" void kernel_launch(void* const* d_in, const int* in_sizes, int n_in,
                              void* d_out, int out_size, void* d_ws, size_t ws_size,
                              hipStream_t stream)
{
    const float* f_re = (const float*)d_in[0];
    const float* f_im = (const float*)d_in[1];
    const float* q_re = (const float*)d_in[2];
    const float* q_im = (const float*)d_in[3];
    const float* p_re = (const float*)d_in[4];
    const float* p_im = (const float*)d_in[5];
    const float* x    = (const float*)d_in[6];
    const float* psi  = (const float*)d_in[7];
    int n = in_sizes[0];   // 16384
    int M = in_sizes[6];   // ~2402 (<= MCAP)

    // workspace layout
    float* gpre = (float*)d_ws;                         // CHUNKS*n
    float* gpim = gpre + (size_t)CHUNKS * n;            // CHUNKS*n
    float* bre  = gpim + (size_t)CHUNKS * n;            // n
    float* bim  = bre + n;                              // n
    unsigned long long* pres = (unsigned long long*)(bim + n); // 1024 u64
    float* loss    = (float*)(pres + PRES_WORDS);
    int*   k3done  = (int*)(loss + 1);
    int*   fin     = k3done + 1;

    // zero pres + loss + counters (8.2 KB)
    hipMemsetAsync(pres, 0, PRES_WORDS * sizeof(unsigned long long) + 12, stream);

    int nb = (n + 255) / 256;   // 64 -> gt grid 64 x 8 = 512 blocks, 2/CU
    gt_kernel<<<dim3(nb, CHUNKS), 256, 0, stream>>>(q_re, q_im, p_re, p_im, x, psi,
                                                    pres, bre, bim, gpre, gpim, n, M);
    scatter_loss_kernel<<<nb, 256, 0, stream>>>(f_re, f_im, q_re, q_im, p_re, p_im,
                                                pres, bre, bim, gpre, gpim,
                                                k3done, loss, fin, (float*)d_out, n);
}